// Round 19
// baseline (156.993 us; speedup 1.0000x reference)
//
#include <hip/hip_runtime.h>
#include <math.h>

// VectorQuantizer: N=131072 tokens, K=1024 codes, D=64, fp32.
// Out layout (flat): z_q_st[N*D] | loss | perplexity | indices[N] (as f32)
#define NTOK 131072
#define NEMB 1024
#define DIM  64
#define OUT_LOSS (NTOK * DIM)
#define OUT_PERP (OUT_LOSS + 1)
#define OUT_IDX  (OUT_LOSS + 2)

#define EPS_FLAG 6e-5f   // screen ambiguity margin (frozen; passed r3-r18)

typedef short bf16x8 __attribute__((ext_vector_type(8)));
typedef float f32x4  __attribute__((ext_vector_type(4)));
typedef const __attribute__((address_space(1))) void* gas_t;
typedef __attribute__((address_space(3))) void* las_t;

// ---- numpy fp32 semantics helpers (frozen from round 2 -- PASSED) ----------
__device__ __forceinline__ float sqb(float x) {
    float y = x * x;
    asm volatile("" : "+v"(y));
    return y;
}
// numpy pairwise_sum for n=64 contiguous: 8 accumulators stride 8, then
// ((r0+r1)+(r2+r3))+((r4+r5)+(r6+r7)).
#define NP_PAIRWISE_SQ64(GET, RES)                                     \
    do {                                                               \
        float r0 = sqb(GET(0)), r1 = sqb(GET(1)), r2 = sqb(GET(2)),    \
              r3 = sqb(GET(3)), r4 = sqb(GET(4)), r5 = sqb(GET(5)),    \
              r6 = sqb(GET(6)), r7 = sqb(GET(7));                      \
        _Pragma("unroll")                                              \
        for (int i = 8; i < 64; i += 8) {                              \
            r0 += sqb(GET(i + 0)); r1 += sqb(GET(i + 1));              \
            r2 += sqb(GET(i + 2)); r3 += sqb(GET(i + 3));              \
            r4 += sqb(GET(i + 4)); r5 += sqb(GET(i + 5));              \
            r6 += sqb(GET(i + 6)); r7 += sqb(GET(i + 7));              \
        }                                                              \
        RES = ((r0 + r1) + (r2 + r3)) + ((r4 + r5) + (r6 + r7));       \
    } while (0)

__device__ __forceinline__ unsigned short f2bf_rne(float x) {
    unsigned u = __float_as_uint(x);
    u += 0x7FFFu + ((u >> 16) & 1u);   // round-to-nearest-even
    return (unsigned short)(u >> 16);
}
__device__ __forceinline__ float bf2f(unsigned short b) {
    return __uint_as_float(((unsigned)b) << 16);
}

// ws layout (bytes):
//   0:      sse double
//   64:     counts int[1024*16]  (64 KiB, one counter per 64B line)
//   65600:  done int
//   65664:  h float[1024]        (4 KiB)
//   69760:  ch bf16[1024*64]     (128 KiB)
//   200832: cl bf16[1024*64]     (128 KiB)

// Kernel 0: h[k] np-exact; ch/cl bf16 split of (-2c); block 0 zeroes accums.
__global__ void vq_prep(const float* __restrict__ cb, float* __restrict__ h,
                        unsigned short* __restrict__ ch, unsigned short* __restrict__ cl,
                        double* __restrict__ sse, int* __restrict__ counts,
                        int* __restrict__ done) {
    if (blockIdx.x == 0) {
        if (threadIdx.x == 0) { *sse = 0.0; *done = 0; }
        for (int i = threadIdx.x; i < NEMB * 16; i += 256) counts[i] = 0;
    }
    int k = blockIdx.x * 256 + threadIdx.x;
    if (k >= NEMB) return;
    float c[64];
    const float4* p = (const float4*)(cb + k * DIM);
#pragma unroll
    for (int q = 0; q < 16; ++q) {
        float4 v = p[q];
        c[4 * q] = v.x; c[4 * q + 1] = v.y; c[4 * q + 2] = v.z; c[4 * q + 3] = v.w;
    }
    float hk;
#define GETC(d) (c[d])
    NP_PAIRWISE_SQ64(GETC, hk);
#undef GETC
    h[k] = hk;
#pragma unroll
    for (int b = 0; b < 8; ++b) {
        unsigned uhv[4], ulv[4];
#pragma unroll
        for (int e = 0; e < 4; ++e) {
            float x0 = -2.0f * c[b * 8 + e * 2 + 0];
            float x1 = -2.0f * c[b * 8 + e * 2 + 1];
            unsigned short h0 = f2bf_rne(x0), h1 = f2bf_rne(x1);
            unsigned short l0 = f2bf_rne(x0 - bf2f(h0)), l1 = f2bf_rne(x1 - bf2f(h1));
            uhv[e] = (unsigned)h0 | ((unsigned)h1 << 16);
            ulv[e] = (unsigned)l0 | ((unsigned)l1 << 16);
        }
        *(uint4*)(ch + k * 64 + b * 8) = make_uint4(uhv[0], uhv[1], uhv[2], uhv[3]);
        *(uint4*)(cl + k * 64 + b * 8) = make_uint4(ulv[0], ulv[1], ulv[2], ulv[3]);
    }
}

// Kernel 1: MFMA screen. r19 change: 4 token-tiles per wave (64 tokens) ->
// each ds_read feeds 4 tiles, halving LDS traffic/token and codebook fetch
// (256 blocks). Per-tile 6-MFMA chains verbatim -> bit-identical scores.
// Single streaming top-2 per tile (exact, order-independent; ties flagged ->
// rescued exactly). Counted-vmcnt pipeline (r18) + register-fed gather (r16).
__global__ __launch_bounds__(512, 4) void vq_screen(
    const float*          __restrict__ ze,
    const float*          __restrict__ cb,
    const unsigned short* __restrict__ ch_g,
    const unsigned short* __restrict__ cl_g,
    const float*          __restrict__ h_g,
    float*                __restrict__ out,
    double*               __restrict__ sse_g,
    int*                  __restrict__ counts) {
    // LDS: 3 x 16KB chunk buffers | h 4KB @49152 | red 64B @53312
    __shared__ __align__(16) char lds[53376];
    const int tid  = threadIdx.x;
    const int lane = tid & 63;
    const int wid  = tid >> 6;
    const int col  = lane & 15;
    const int grp  = lane >> 4;
    const int tbase = blockIdx.x * 512 + wid * 64;

    // pre-swizzled global source offset (involution row,col^row&7 -- r17)
    const int srow = tid >> 3, scol = tid & 7;
    const int srcoff = (srow * 8 + (scol ^ (srow & 7))) * 16;

    bf16x8 zh[4][2], zl[4][2];
#pragma unroll
    for (int tt = 0; tt < 4; ++tt)
#pragma unroll
        for (int s = 0; s < 2; ++s) {
            const float* zp = ze + (size_t)(tbase + tt * 16 + col) * 64 + s * 32 + grp * 8;
            float4 v0 = *(const float4*)(zp);
            float4 v1 = *(const float4*)(zp + 4);
            float zv[8] = {v0.x, v0.y, v0.z, v0.w, v1.x, v1.y, v1.z, v1.w};
            bf16x8 hfr, lfr;
#pragma unroll
            for (int j = 0; j < 8; ++j) {
                unsigned short hb = f2bf_rne(zv[j]);
                unsigned short lb = f2bf_rne(zv[j] - bf2f(hb));
                hfr[j] = (short)hb;
                lfr[j] = (short)lb;
            }
            zh[tt][s] = hfr;
            zl[tt][s] = lfr;
        }

    float m1[4] = {INFINITY, INFINITY, INFINITY, INFINITY};
    float m2[4] = {INFINITY, INFINITY, INFINITY, INFINITY};
    int   ki[4] = {0, 0, 0, 0};

    // STAGE = exactly 2 DMA loads per thread (uniform across waves)
#define STAGE(cc, b)                                                           \
    do {                                                                       \
        __builtin_amdgcn_global_load_lds(                                      \
            (gas_t)((const char*)ch_g + (cc) * 8192 + srcoff),                 \
            (las_t)(lds + (b) * 16384 + wid * 1024), 16, 0, 0);                \
        __builtin_amdgcn_global_load_lds(                                      \
            (gas_t)((const char*)cl_g + (cc) * 8192 + srcoff),                 \
            (las_t)(lds + (b) * 16384 + 8192 + wid * 1024), 16, 0, 0);         \
    } while (0)

#define COMPUTE(cc, b)                                                         \
    do {                                                                       \
        _Pragma("unroll")                                                      \
        for (int ct = 0; ct < 4; ++ct) {                                       \
            const int arow = (b) * 16384 + ct * 2048 + col * 128;              \
            bf16x8 ach0 = *(const bf16x8*)(lds + arow + ((((0 * 4) + grp) ^ (col & 7)) << 4)); \
            bf16x8 ach1 = *(const bf16x8*)(lds + arow + ((((1 * 4) + grp) ^ (col & 7)) << 4)); \
            bf16x8 acl0 = *(const bf16x8*)(lds + arow + 8192 + ((((0 * 4) + grp) ^ (col & 7)) << 4)); \
            bf16x8 acl1 = *(const bf16x8*)(lds + arow + 8192 + ((((1 * 4) + grp) ^ (col & 7)) << 4)); \
            f32x4 hv = *(const f32x4*)(lds + 49152 + (cc) * 256 + ct * 64 + grp * 16); \
            const int kb = (cc) * 64 + ct * 16 + grp * 4;                      \
            _Pragma("unroll")                                                  \
            for (int tt = 0; tt < 4; ++tt) {                                   \
                f32x4 acc = hv;                                                \
                acc = __builtin_amdgcn_mfma_f32_16x16x32_bf16(ach0, zh[tt][0], acc, 0, 0, 0); \
                acc = __builtin_amdgcn_mfma_f32_16x16x32_bf16(ach1, zh[tt][1], acc, 0, 0, 0); \
                acc = __builtin_amdgcn_mfma_f32_16x16x32_bf16(ach0, zl[tt][0], acc, 0, 0, 0); \
                acc = __builtin_amdgcn_mfma_f32_16x16x32_bf16(ach1, zl[tt][1], acc, 0, 0, 0); \
                acc = __builtin_amdgcn_mfma_f32_16x16x32_bf16(acl0, zh[tt][0], acc, 0, 0, 0); \
                acc = __builtin_amdgcn_mfma_f32_16x16x32_bf16(acl1, zh[tt][1], acc, 0, 0, 0); \
                _Pragma("unroll")                                              \
                for (int j = 0; j < 4; ++j) {                                  \
                    float s = acc[j];                                          \
                    m2[tt] = fminf(m2[tt], fmaxf(s, m1[tt]));                  \
                    ki[tt] = (s < m1[tt]) ? (kb + j) : ki[tt];                 \
                    m1[tt] = fminf(m1[tt], s);                                 \
                }                                                              \
            }                                                                  \
        }                                                                      \
    } while (0)

    // chunk boundary: counted wait (loads for cc+1 stay in flight) + barrier
#define CHUNK(cc, W)                                                           \
    do {                                                                       \
        asm volatile("s_waitcnt vmcnt(" #W ")" ::: "memory");                  \
        __builtin_amdgcn_s_barrier();                                          \
        __builtin_amdgcn_sched_barrier(0);                                     \
        if ((cc) + 2 < 16) STAGE((cc) + 2, ((cc) + 2) % 3);                    \
        COMPUTE(cc, (cc) % 3);                                                 \
    } while (0)

    // prologue: h (2 uniform width-4 DMAs, oldest) + chunks 0,1
    __builtin_amdgcn_global_load_lds((gas_t)(h_g + tid),
                                     (las_t)(lds + 49152 + wid * 256), 4, 0, 0);
    __builtin_amdgcn_global_load_lds((gas_t)(h_g + 512 + tid),
                                     (las_t)(lds + 49152 + 2048 + wid * 256), 4, 0, 0);
    STAGE(0, 0);
    STAGE(1, 1);

    CHUNK(0, 2);  CHUNK(1, 2);  CHUNK(2, 2);  CHUNK(3, 2);
    CHUNK(4, 2);  CHUNK(5, 2);  CHUNK(6, 2);  CHUNK(7, 2);
    CHUNK(8, 2);  CHUNK(9, 2);  CHUNK(10, 2); CHUNK(11, 2);
    CHUNK(12, 2); CHUNK(13, 2); CHUNK(14, 2); CHUNK(15, 0);

#pragma unroll
    for (int d = 16; d <= 32; d <<= 1) {
#pragma unroll
        for (int tt = 0; tt < 4; ++tt) {
            float om1 = __shfl_xor(m1[tt], d, 64);
            float om2 = __shfl_xor(m2[tt], d, 64);
            int   oki = __shfl_xor(ki[tt], d, 64);
            m2[tt] = fminf(fminf(m2[tt], om2), fmaxf(m1[tt], om1));
            ki[tt] = (om1 < m1[tt]) ? oki : ki[tt];
            m1[tt] = fminf(m1[tt], om1);
        }
    }
    // after butterfly, every lane holds m1/m2/ki for token col = lane&15
    unsigned flagpack = ((m2[0] - m1[0] < EPS_FLAG) ? 1u : 0u)
                      | ((m2[1] - m1[1] < EPS_FLAG) ? 2u : 0u)
                      | ((m2[2] - m1[2] < EPS_FLAG) ? 4u : 0u)
                      | ((m2[3] - m1[3] < EPS_FLAG) ? 8u : 0u);
    if (lane < 16) {
#pragma unroll
        for (int tt = 0; tt < 4; ++tt) {
            int t = tbase + tt * 16 + lane;
            bool flag = (flagpack >> tt) & 1u;
            out[OUT_IDX + t] = flag ? -(float)(ki[tt] + 1) : (float)ki[tt];
        }
    }

    // ---- register-fed float4 gather/SSE/histogram for UNFLAGGED tokens ----
    double lsse = 0.0;
    const int d4 = lane & 15;
#pragma unroll
    for (int iter = 0; iter < 16; ++iter) {
        const int j   = iter * 4 + grp;       // row in [0,64)
        const int tt  = j >> 4;               // uniform per iter
        const int src = j & 15;
        int k = __shfl(ki[tt], src, 64);
        unsigned fp = __shfl(flagpack, src, 64);
        if (!((fp >> tt) & 1u)) {
            const int t = tbase + j;
            float4 q  = *(const float4*)(cb + k * DIM + d4 * 4);
            float4 zv = *(const float4*)(ze + (size_t)t * DIM + d4 * 4);
            *(float4*)(out + (size_t)t * DIM + d4 * 4) = q;
            double dx = (double)q.x - (double)zv.x;
            double dy = (double)q.y - (double)zv.y;
            double dz = (double)q.z - (double)zv.z;
            double dw = (double)q.w - (double)zv.w;
            lsse = fma(dx, dx, lsse); lsse = fma(dy, dy, lsse);
            lsse = fma(dz, dz, lsse); lsse = fma(dw, dw, lsse);
            if (d4 == 0) atomicAdd(&counts[k * 16], 1);   // one per row
        }
    }
#pragma unroll
    for (int off = 32; off > 0; off >>= 1)
        lsse += __shfl_down(lsse, off, 64);
    double* red = (double*)(lds + 53312);
    if (lane == 0) red[wid] = lsse;
    __syncthreads();
    if (tid == 0) {
        double bs = ((red[0] + red[1]) + (red[2] + red[3]))
                  + ((red[4] + red[5]) + (red[6] + red[7]));
        atomicAdd(sse_g, bs);
    }
}

// Kernel 2: rescue (r16-r18 VERBATIM -- PASSED). Block owns 512 tokens, local
// worklist, LDS-staged full-codebook exact scan, end-to-end ownership,
// done-counter last-block finalize.
__global__ __launch_bounds__(512) void vq_rescue(
    const float* __restrict__ ze, const float* __restrict__ cb,
    const float* __restrict__ h_g, float* __restrict__ out,
    double* __restrict__ sse_g, int* __restrict__ counts,
    int* __restrict__ done) {
    __shared__ __align__(16) float4 cbl[512 * 17];          // 139,264 B
    __shared__ float zst[8][64];
    __shared__ unsigned long long keys[8][64];
    __shared__ float hl[NEMB];
    __shared__ int loc[512];
    __shared__ int nloc;
    __shared__ double red[8];
    __shared__ int flagS;
    const int tid  = threadIdx.x;
    const int lane = tid & 63;
    const int wid  = tid >> 6;
    const int tbase = blockIdx.x * 512;

    if (tid == 0) nloc = 0;
    for (int i = tid; i < NEMB; i += 512) hl[i] = h_g[i];
    __syncthreads();
    float fidx = out[OUT_IDX + tbase + tid];
    if (fidx < 0.0f) { int s = atomicAdd(&nloc, 1); loc[s] = tid; }
    __syncthreads();
    const int nq = nloc;
    double lsse = 0.0;

    if (nq > 0) {
        const float4* cb4 = (const float4*)cb;
        for (int hf = 0; hf < 2; ++hf) {
            __syncthreads();
#pragma unroll
            for (int j = 0; j < 16; ++j) {
                int f = tid + j * 512;
                int code = f >> 4, d4 = f & 15;
                cbl[code * 17 + d4] = cb4[(size_t)(hf * 512 + code) * 16 + d4];
            }
            __syncthreads();

            for (int i = wid; i < nq; i += 8) {
                const int t = tbase + loc[i];
                const int slot = i >> 3;

                zst[wid][lane] = ze[(size_t)t * 64 + lane];
                __builtin_amdgcn_wave_barrier();
                asm volatile("s_waitcnt lgkmcnt(0)" ::: "memory");
                __builtin_amdgcn_sched_barrier(0);

                float sz;
#define GZ(d) (zst[wid][d])
                NP_PAIRWISE_SQ64(GZ, sz);
#undef GZ

                float acc[8] = {0.f, 0.f, 0.f, 0.f, 0.f, 0.f, 0.f, 0.f};
                const float4* zr4 = (const float4*)zst[wid];
#pragma unroll
                for (int d4 = 0; d4 < 16; ++d4) {
                    float4 zq = zr4[d4];
#pragma unroll
                    for (int cc = 0; cc < 8; ++cc) {
                        float4 cv = cbl[(lane + 64 * cc) * 17 + d4];
                        acc[cc] = fmaf(cv.x, zq.x, acc[cc]);
                        acc[cc] = fmaf(cv.y, zq.y, acc[cc]);
                        acc[cc] = fmaf(cv.z, zq.z, acc[cc]);
                        acc[cc] = fmaf(cv.w, zq.w, acc[cc]);
                    }
                }
                unsigned long long key = ~0ull;
#pragma unroll
                for (int cc = 0; cc < 8; ++cc) {
                    unsigned k = (unsigned)(hf * 512 + lane + 64 * cc);
                    float dk = (sz + hl[k]) - 2.0f * acc[cc];   // frozen formula
                    unsigned long long c =
                        ((unsigned long long)__float_as_uint(dk) << 32) | k;
                    key = c < key ? c : key;
                }
#pragma unroll
                for (int dd = 1; dd < 64; dd <<= 1) {
                    unsigned long long o = __shfl_xor(key, dd, 64);
                    key = o < key ? o : key;
                }
                if (hf == 0) {
                    if (lane == 0) keys[wid][slot] = key;
                } else {
                    unsigned long long k0 = keys[wid][slot];  // LDS broadcast
                    if (k0 < key) key = k0;
                    int newk = (int)(unsigned)(key & 0xFFFFFFFFull);
                    float q  = cb[newk * 64 + lane];
                    float zv = zst[wid][lane];
                    out[(size_t)t * 64 + lane] = q;
                    double diff = (double)q - (double)zv;
                    lsse = fma(diff, diff, lsse);
                    if (lane == 0) {
                        out[OUT_IDX + t] = (float)newk;
                        atomicAdd(&counts[newk * 16], 1);
                    }
                }
            }
        }
    }

#pragma unroll
    for (int off = 32; off > 0; off >>= 1)
        lsse += __shfl_down(lsse, off, 64);
    if (lane == 0) red[wid] = lsse;
    __syncthreads();
    if (tid == 0) {
        double bs = ((red[0] + red[1]) + (red[2] + red[3]))
                  + ((red[4] + red[5]) + (red[6] + red[7]));
        if (bs != 0.0) atomicAdd(sse_g, bs);
        __threadfence();
        flagS = (atomicAdd(done, 1) == 255);
    }
    __syncthreads();

    if (flagS) {
        __threadfence();
        double* red2 = (double*)cbl;   // staging LDS dead here
        double local = 0.0;
        for (int k = tid; k < NEMB; k += 512) {
            int cv = __hip_atomic_load(&counts[k * 16], __ATOMIC_RELAXED, __HIP_MEMORY_SCOPE_AGENT);
            double p = (double)cv / (double)NTOK;
            local += p * log(p + 1e-10);
        }
        red2[tid] = local;
        __syncthreads();
        for (int s = 256; s > 0; s >>= 1) {
            if (tid < s) red2[tid] += red2[tid + s];
            __syncthreads();
        }
        if (tid == 0) {
            double sv = __hip_atomic_load(sse_g, __ATOMIC_RELAXED, __HIP_MEMORY_SCOPE_AGENT);
            double mse = sv / ((double)NTOK * (double)DIM);
            out[OUT_LOSS] = (float)(1.25 * mse);
            out[OUT_PERP] = (float)exp(-red2[0]);
        }
    }
}

extern "C" void kernel_launch(void* const* d_in, const int* in_sizes, int n_in,
                              void* d_out, int out_size, void* d_ws, size_t ws_size,
                              hipStream_t stream) {
    const float* ze = (const float*)d_in[0];
    const float* cb = (const float*)d_in[1];
    float* out = (float*)d_out;

    char* w = (char*)d_ws;
    double*         sse    = (double*)w;                     // @0
    int*            counts = (int*)(w + 64);                 // 64 KiB (padded)
    int*            done   = (int*)(w + 65600);
    float*          h      = (float*)(w + 65664);            // 4 KiB
    unsigned short* ch     = (unsigned short*)(w + 69760);   // 128 KiB
    unsigned short* cl     = (unsigned short*)(w + 200832);  // 128 KiB

    vq_prep<<<NEMB / 256, 256, 0, stream>>>(cb, h, ch, cl, sse, counts, done);
    vq_screen<<<NTOK / 512, 512, 0, stream>>>(ze, cb, ch, cl, h, out, sse, counts);
    vq_rescue<<<NTOK / 512, 512, 0, stream>>>(ze, cb, h, out, sse, counts, done);
}

// Round 20
// 148.601 us; speedup vs baseline: 1.0565x; 1.0565x over previous
//
#include <hip/hip_runtime.h>
#include <math.h>

// VectorQuantizer: N=131072 tokens, K=1024 codes, D=64, fp32.
// Out layout (flat): z_q_st[N*D] | loss | perplexity | indices[N] (as f32)
#define NTOK 131072
#define NEMB 1024
#define DIM  64
#define OUT_LOSS (NTOK * DIM)
#define OUT_PERP (OUT_LOSS + 1)
#define OUT_IDX  (OUT_LOSS + 2)

// r20: single-split screen (ch only). Score error sigma ~2.1e-5 (see journal);
// EPS = 1.5e-4 ~ 7 sigma. Ties/near-ties still resolved exactly by rescue.
#define EPS_FLAG 1.5e-4f

typedef short bf16x8 __attribute__((ext_vector_type(8)));
typedef float f32x4  __attribute__((ext_vector_type(4)));
typedef const __attribute__((address_space(1))) void* gas_t;
typedef __attribute__((address_space(3))) void* las_t;

// ---- numpy fp32 semantics helpers (frozen from round 2 -- PASSED) ----------
__device__ __forceinline__ float sqb(float x) {
    float y = x * x;
    asm volatile("" : "+v"(y));
    return y;
}
// numpy pairwise_sum for n=64 contiguous: 8 accumulators stride 8, then
// ((r0+r1)+(r2+r3))+((r4+r5)+(r6+r7)).
#define NP_PAIRWISE_SQ64(GET, RES)                                     \
    do {                                                               \
        float r0 = sqb(GET(0)), r1 = sqb(GET(1)), r2 = sqb(GET(2)),    \
              r3 = sqb(GET(3)), r4 = sqb(GET(4)), r5 = sqb(GET(5)),    \
              r6 = sqb(GET(6)), r7 = sqb(GET(7));                      \
        _Pragma("unroll")                                              \
        for (int i = 8; i < 64; i += 8) {                              \
            r0 += sqb(GET(i + 0)); r1 += sqb(GET(i + 1));              \
            r2 += sqb(GET(i + 2)); r3 += sqb(GET(i + 3));              \
            r4 += sqb(GET(i + 4)); r5 += sqb(GET(i + 5));              \
            r6 += sqb(GET(i + 6)); r7 += sqb(GET(i + 7));              \
        }                                                              \
        RES = ((r0 + r1) + (r2 + r3)) + ((r4 + r5) + (r6 + r7));       \
    } while (0)

__device__ __forceinline__ unsigned short f2bf_rne(float x) {
    unsigned u = __float_as_uint(x);
    u += 0x7FFFu + ((u >> 16) & 1u);   // round-to-nearest-even
    return (unsigned short)(u >> 16);
}
__device__ __forceinline__ float bf2f(unsigned short b) {
    return __uint_as_float(((unsigned)b) << 16);
}

// ws layout (bytes):
//   0:      sse double
//   64:     counts int[1024*16]  (64 KiB, one counter per 64B line)
//   65600:  done int
//   65664:  h float[1024]        (4 KiB)
//   69760:  ch bf16[1024*64]     (128 KiB)

// Kernel 0: h[k] np-exact; ch = bf16 split (high only) of (-2c); block 0
// zeroes accums.
__global__ void vq_prep(const float* __restrict__ cb, float* __restrict__ h,
                        unsigned short* __restrict__ ch,
                        double* __restrict__ sse, int* __restrict__ counts,
                        int* __restrict__ done) {
    if (blockIdx.x == 0) {
        if (threadIdx.x == 0) { *sse = 0.0; *done = 0; }
        for (int i = threadIdx.x; i < NEMB * 16; i += 256) counts[i] = 0;
    }
    int k = blockIdx.x * 256 + threadIdx.x;
    if (k >= NEMB) return;
    float c[64];
    const float4* p = (const float4*)(cb + k * DIM);
#pragma unroll
    for (int q = 0; q < 16; ++q) {
        float4 v = p[q];
        c[4 * q] = v.x; c[4 * q + 1] = v.y; c[4 * q + 2] = v.z; c[4 * q + 3] = v.w;
    }
    float hk;
#define GETC(d) (c[d])
    NP_PAIRWISE_SQ64(GETC, hk);
#undef GETC
    h[k] = hk;
#pragma unroll
    for (int b = 0; b < 8; ++b) {
        unsigned uhv[4];
#pragma unroll
        for (int e = 0; e < 4; ++e) {
            float x0 = -2.0f * c[b * 8 + e * 2 + 0];
            float x1 = -2.0f * c[b * 8 + e * 2 + 1];
            unsigned short h0 = f2bf_rne(x0), h1 = f2bf_rne(x1);
            uhv[e] = (unsigned)h0 | ((unsigned)h1 << 16);
        }
        *(uint4*)(ch + k * 64 + b * 8) = make_uint4(uhv[0], uhv[1], uhv[2], uhv[3]);
    }
}

// Kernel 1: MFMA screen, single-split. r18 structure (2 tiles/wave, proven),
// ch only: 4 MFMA/tile, 8KB chunks, 1 DMA per STAGE, counted-vmcnt W=1.
// Register-fed float4 gather/SSE/histogram epilogue (r16, PASSED).
__global__ __launch_bounds__(512) void vq_screen(
    const float*          __restrict__ ze,
    const float*          __restrict__ cb,
    const unsigned short* __restrict__ ch_g,
    const float*          __restrict__ h_g,
    float*                __restrict__ out,
    double*               __restrict__ sse_g,
    int*                  __restrict__ counts) {
    // LDS: 3 x 8KB chunk buffers @0 | h 4KB @24576 | red 64B @28672
    __shared__ __align__(16) char lds[28736];
    const int tid  = threadIdx.x;
    const int lane = tid & 63;
    const int wid  = tid >> 6;
    const int col  = lane & 15;
    const int grp  = lane >> 4;
    const int tbase = blockIdx.x * 256 + wid * 32;

    // pre-swizzled global source offset (involution row,col^row&7 -- r17)
    const int srow = tid >> 3, scol = tid & 7;
    const int srcoff = (srow * 8 + (scol ^ (srow & 7))) * 16;

    bf16x8 zh[2][2], zl[2][2];
#pragma unroll
    for (int tt = 0; tt < 2; ++tt)
#pragma unroll
        for (int s = 0; s < 2; ++s) {
            const float* zp = ze + (size_t)(tbase + tt * 16 + col) * 64 + s * 32 + grp * 8;
            float4 v0 = *(const float4*)(zp);
            float4 v1 = *(const float4*)(zp + 4);
            float zv[8] = {v0.x, v0.y, v0.z, v0.w, v1.x, v1.y, v1.z, v1.w};
            bf16x8 hfr, lfr;
#pragma unroll
            for (int j = 0; j < 8; ++j) {
                unsigned short hb = f2bf_rne(zv[j]);
                unsigned short lb = f2bf_rne(zv[j] - bf2f(hb));
                hfr[j] = (short)hb;
                lfr[j] = (short)lb;
            }
            zh[tt][s] = hfr;
            zl[tt][s] = lfr;
        }

    float m1[2] = {INFINITY, INFINITY}, m2[2] = {INFINITY, INFINITY};
    int   ki[2] = {0, 0};

    // STAGE = exactly 1 DMA load per thread (uniform across waves)
#define STAGE(cc, b)                                                           \
    do {                                                                       \
        __builtin_amdgcn_global_load_lds(                                      \
            (gas_t)((const char*)ch_g + (cc) * 8192 + srcoff),                 \
            (las_t)(lds + (b) * 8192 + wid * 1024), 16, 0, 0);                 \
    } while (0)

#define COMPUTE(cc, b)                                                         \
    do {                                                                       \
        _Pragma("unroll")                                                      \
        for (int ct = 0; ct < 4; ++ct) {                                       \
            const int arow = (b) * 8192 + ct * 2048 + col * 128;               \
            bf16x8 ach0 = *(const bf16x8*)(lds + arow + ((((0 * 4) + grp) ^ (col & 7)) << 4)); \
            bf16x8 ach1 = *(const bf16x8*)(lds + arow + ((((1 * 4) + grp) ^ (col & 7)) << 4)); \
            f32x4 hv = *(const f32x4*)(lds + 24576 + (cc) * 256 + ct * 64 + grp * 16); \
            f32x4 acc0 = hv, acc1 = hv;                                        \
            acc0 = __builtin_amdgcn_mfma_f32_16x16x32_bf16(ach0, zh[0][0], acc0, 0, 0, 0); \
            acc1 = __builtin_amdgcn_mfma_f32_16x16x32_bf16(ach0, zh[1][0], acc1, 0, 0, 0); \
            acc0 = __builtin_amdgcn_mfma_f32_16x16x32_bf16(ach1, zh[0][1], acc0, 0, 0, 0); \
            acc1 = __builtin_amdgcn_mfma_f32_16x16x32_bf16(ach1, zh[1][1], acc1, 0, 0, 0); \
            acc0 = __builtin_amdgcn_mfma_f32_16x16x32_bf16(ach0, zl[0][0], acc0, 0, 0, 0); \
            acc1 = __builtin_amdgcn_mfma_f32_16x16x32_bf16(ach0, zl[1][0], acc1, 0, 0, 0); \
            acc0 = __builtin_amdgcn_mfma_f32_16x16x32_bf16(ach1, zl[0][1], acc0, 0, 0, 0); \
            acc1 = __builtin_amdgcn_mfma_f32_16x16x32_bf16(ach1, zl[1][1], acc1, 0, 0, 0); \
            const int kb = (cc) * 64 + ct * 16 + grp * 4;                      \
            _Pragma("unroll")                                                  \
            for (int j = 0; j < 4; ++j) {                                      \
                float s0 = acc0[j], s1 = acc1[j];                              \
                bool lt0 = s0 < m1[0], lt1 = s1 < m1[1];                       \
                m2[0] = fminf(m2[0], fmaxf(s0, m1[0]));                        \
                m2[1] = fminf(m2[1], fmaxf(s1, m1[1]));                        \
                ki[0] = lt0 ? (kb + j) : ki[0];                                \
                ki[1] = lt1 ? (kb + j) : ki[1];                                \
                m1[0] = fminf(m1[0], s0);                                      \
                m1[1] = fminf(m1[1], s1);                                      \
            }                                                                  \
        }                                                                      \
    } while (0)

    // chunk boundary: counted wait (load for cc+1 stays in flight) + barrier
#define CHUNK(cc, W)                                                           \
    do {                                                                       \
        asm volatile("s_waitcnt vmcnt(" #W ")" ::: "memory");                  \
        __builtin_amdgcn_s_barrier();                                          \
        __builtin_amdgcn_sched_barrier(0);                                     \
        if ((cc) + 2 < 16) STAGE((cc) + 2, ((cc) + 2) % 3);                    \
        COMPUTE(cc, (cc) % 3);                                                 \
    } while (0)

    // prologue: h (2 uniform width-4 DMAs, oldest in queue) + chunks 0,1
    __builtin_amdgcn_global_load_lds((gas_t)(h_g + tid),
                                     (las_t)(lds + 24576 + wid * 256), 4, 0, 0);
    __builtin_amdgcn_global_load_lds((gas_t)(h_g + 512 + tid),
                                     (las_t)(lds + 24576 + 2048 + wid * 256), 4, 0, 0);
    STAGE(0, 0);
    STAGE(1, 1);

    CHUNK(0, 1);  CHUNK(1, 1);  CHUNK(2, 1);  CHUNK(3, 1);
    CHUNK(4, 1);  CHUNK(5, 1);  CHUNK(6, 1);  CHUNK(7, 1);
    CHUNK(8, 1);  CHUNK(9, 1);  CHUNK(10, 1); CHUNK(11, 1);
    CHUNK(12, 1); CHUNK(13, 1); CHUNK(14, 1); CHUNK(15, 0);

#pragma unroll
    for (int d = 16; d <= 32; d <<= 1) {
#pragma unroll
        for (int tt = 0; tt < 2; ++tt) {
            float om1 = __shfl_xor(m1[tt], d, 64);
            float om2 = __shfl_xor(m2[tt], d, 64);
            int   oki = __shfl_xor(ki[tt], d, 64);
            m2[tt] = fminf(fminf(m2[tt], om2), fmaxf(m1[tt], om1));
            ki[tt] = (om1 < m1[tt]) ? oki : ki[tt];
            m1[tt] = fminf(m1[tt], om1);
        }
    }
    // after butterfly, every lane holds m1/m2/ki for token col = lane&15
    unsigned flagpack = ((m2[0] - m1[0] < EPS_FLAG) ? 1u : 0u)
                      | ((m2[1] - m1[1] < EPS_FLAG) ? 2u : 0u);
    if (lane < 16) {
#pragma unroll
        for (int tt = 0; tt < 2; ++tt) {
            int t = tbase + tt * 16 + lane;
            bool flag = (flagpack >> tt) & 1u;
            out[OUT_IDX + t] = flag ? -(float)(ki[tt] + 1) : (float)ki[tt];
        }
    }

    // ---- register-fed float4 gather/SSE/histogram for UNFLAGGED tokens ----
    double lsse = 0.0;
    const int d4 = lane & 15;
#pragma unroll
    for (int iter = 0; iter < 8; ++iter) {
        const int j   = iter * 4 + grp;       // row in [0,32)
        const int tt  = iter >> 2;            // uniform per iter
        const int src = j & 15;
        int k = __shfl(ki[tt], src, 64);
        unsigned fp = __shfl(flagpack, src, 64);
        if (!((fp >> tt) & 1u)) {
            const int t = tbase + j;
            float4 q  = *(const float4*)(cb + k * DIM + d4 * 4);
            float4 zv = *(const float4*)(ze + (size_t)t * DIM + d4 * 4);
            *(float4*)(out + (size_t)t * DIM + d4 * 4) = q;
            double dx = (double)q.x - (double)zv.x;
            double dy = (double)q.y - (double)zv.y;
            double dz = (double)q.z - (double)zv.z;
            double dw = (double)q.w - (double)zv.w;
            lsse = fma(dx, dx, lsse); lsse = fma(dy, dy, lsse);
            lsse = fma(dz, dz, lsse); lsse = fma(dw, dw, lsse);
            if (d4 == 0) atomicAdd(&counts[k * 16], 1);   // one per row
        }
    }
#pragma unroll
    for (int off = 32; off > 0; off >>= 1)
        lsse += __shfl_down(lsse, off, 64);
    double* red = (double*)(lds + 28672);
    if (lane == 0) red[wid] = lsse;
    __syncthreads();
    if (tid == 0) {
        double bs = ((red[0] + red[1]) + (red[2] + red[3]))
                  + ((red[4] + red[5]) + (red[6] + red[7]));
        atomicAdd(sse_g, bs);
    }
}

// Kernel 2: rescue (r16-r18 VERBATIM -- PASSED; handles larger nq fine).
// Block owns 512 tokens, local worklist, LDS-staged full-codebook exact scan,
// end-to-end ownership, done-counter last-block finalize.
__global__ __launch_bounds__(512) void vq_rescue(
    const float* __restrict__ ze, const float* __restrict__ cb,
    const float* __restrict__ h_g, float* __restrict__ out,
    double* __restrict__ sse_g, int* __restrict__ counts,
    int* __restrict__ done) {
    __shared__ __align__(16) float4 cbl[512 * 17];          // 139,264 B
    __shared__ float zst[8][64];
    __shared__ unsigned long long keys[8][64];
    __shared__ float hl[NEMB];
    __shared__ int loc[512];
    __shared__ int nloc;
    __shared__ double red[8];
    __shared__ int flagS;
    const int tid  = threadIdx.x;
    const int lane = tid & 63;
    const int wid  = tid >> 6;
    const int tbase = blockIdx.x * 512;

    if (tid == 0) nloc = 0;
    for (int i = tid; i < NEMB; i += 512) hl[i] = h_g[i];
    __syncthreads();
    float fidx = out[OUT_IDX + tbase + tid];
    if (fidx < 0.0f) { int s = atomicAdd(&nloc, 1); loc[s] = tid; }
    __syncthreads();
    const int nq = nloc;
    double lsse = 0.0;

    if (nq > 0) {
        const float4* cb4 = (const float4*)cb;
        for (int hf = 0; hf < 2; ++hf) {
            __syncthreads();
#pragma unroll
            for (int j = 0; j < 16; ++j) {
                int f = tid + j * 512;
                int code = f >> 4, d4 = f & 15;
                cbl[code * 17 + d4] = cb4[(size_t)(hf * 512 + code) * 16 + d4];
            }
            __syncthreads();

            for (int i = wid; i < nq; i += 8) {
                const int t = tbase + loc[i];
                const int slot = i >> 3;

                zst[wid][lane] = ze[(size_t)t * 64 + lane];
                __builtin_amdgcn_wave_barrier();
                asm volatile("s_waitcnt lgkmcnt(0)" ::: "memory");
                __builtin_amdgcn_sched_barrier(0);

                float sz;
#define GZ(d) (zst[wid][d])
                NP_PAIRWISE_SQ64(GZ, sz);
#undef GZ

                float acc[8] = {0.f, 0.f, 0.f, 0.f, 0.f, 0.f, 0.f, 0.f};
                const float4* zr4 = (const float4*)zst[wid];
#pragma unroll
                for (int d4 = 0; d4 < 16; ++d4) {
                    float4 zq = zr4[d4];
#pragma unroll
                    for (int cc = 0; cc < 8; ++cc) {
                        float4 cv = cbl[(lane + 64 * cc) * 17 + d4];
                        acc[cc] = fmaf(cv.x, zq.x, acc[cc]);
                        acc[cc] = fmaf(cv.y, zq.y, acc[cc]);
                        acc[cc] = fmaf(cv.z, zq.z, acc[cc]);
                        acc[cc] = fmaf(cv.w, zq.w, acc[cc]);
                    }
                }
                unsigned long long key = ~0ull;
#pragma unroll
                for (int cc = 0; cc < 8; ++cc) {
                    unsigned k = (unsigned)(hf * 512 + lane + 64 * cc);
                    float dk = (sz + hl[k]) - 2.0f * acc[cc];   // frozen formula
                    unsigned long long c =
                        ((unsigned long long)__float_as_uint(dk) << 32) | k;
                    key = c < key ? c : key;
                }
#pragma unroll
                for (int dd = 1; dd < 64; dd <<= 1) {
                    unsigned long long o = __shfl_xor(key, dd, 64);
                    key = o < key ? o : key;
                }
                if (hf == 0) {
                    if (lane == 0) keys[wid][slot] = key;
                } else {
                    unsigned long long k0 = keys[wid][slot];  // LDS broadcast
                    if (k0 < key) key = k0;
                    int newk = (int)(unsigned)(key & 0xFFFFFFFFull);
                    float q  = cb[newk * 64 + lane];
                    float zv = zst[wid][lane];
                    out[(size_t)t * 64 + lane] = q;
                    double diff = (double)q - (double)zv;
                    lsse = fma(diff, diff, lsse);
                    if (lane == 0) {
                        out[OUT_IDX + t] = (float)newk;
                        atomicAdd(&counts[newk * 16], 1);
                    }
                }
            }
        }
    }

#pragma unroll
    for (int off = 32; off > 0; off >>= 1)
        lsse += __shfl_down(lsse, off, 64);
    if (lane == 0) red[wid] = lsse;
    __syncthreads();
    if (tid == 0) {
        double bs = ((red[0] + red[1]) + (red[2] + red[3]))
                  + ((red[4] + red[5]) + (red[6] + red[7]));
        if (bs != 0.0) atomicAdd(sse_g, bs);
        __threadfence();
        flagS = (atomicAdd(done, 1) == 255);
    }
    __syncthreads();

    if (flagS) {
        __threadfence();
        double* red2 = (double*)cbl;   // staging LDS dead here
        double local = 0.0;
        for (int k = tid; k < NEMB; k += 512) {
            int cv = __hip_atomic_load(&counts[k * 16], __ATOMIC_RELAXED, __HIP_MEMORY_SCOPE_AGENT);
            double p = (double)cv / (double)NTOK;
            local += p * log(p + 1e-10);
        }
        red2[tid] = local;
        __syncthreads();
        for (int s = 256; s > 0; s >>= 1) {
            if (tid < s) red2[tid] += red2[tid + s];
            __syncthreads();
        }
        if (tid == 0) {
            double sv = __hip_atomic_load(sse_g, __ATOMIC_RELAXED, __HIP_MEMORY_SCOPE_AGENT);
            double mse = sv / ((double)NTOK * (double)DIM);
            out[OUT_LOSS] = (float)(1.25 * mse);
            out[OUT_PERP] = (float)exp(-red2[0]);
        }
    }
}

extern "C" void kernel_launch(void* const* d_in, const int* in_sizes, int n_in,
                              void* d_out, int out_size, void* d_ws, size_t ws_size,
                              hipStream_t stream) {
    const float* ze = (const float*)d_in[0];
    const float* cb = (const float*)d_in[1];
    float* out = (float*)d_out;

    char* w = (char*)d_ws;
    double*         sse    = (double*)w;                     // @0
    int*            counts = (int*)(w + 64);                 // 64 KiB (padded)
    int*            done   = (int*)(w + 65600);
    float*          h      = (float*)(w + 65664);            // 4 KiB
    unsigned short* ch     = (unsigned short*)(w + 69760);   // 128 KiB

    vq_prep<<<NEMB / 256, 256, 0, stream>>>(cb, h, ch, sse, counts, done);
    vq_screen<<<NTOK / 256, 512, 0, stream>>>(ze, cb, ch, h, out, sse, counts);
    vq_rescue<<<NTOK / 512, 512, 0, stream>>>(ze, cb, h, out, sse, counts, done);
}

// Round 21
// 133.661 us; speedup vs baseline: 1.1746x; 1.1118x over previous
//
#include <hip/hip_runtime.h>
#include <math.h>

// VectorQuantizer: N=131072 tokens, K=1024 codes, D=64, fp32.
// Out layout (flat): z_q_st[N*D] | loss | perplexity | indices[N] (as f32)
#define NTOK 131072
#define NEMB 1024
#define DIM  64
#define OUT_LOSS (NTOK * DIM)
#define OUT_PERP (OUT_LOSS + 1)
#define OUT_IDX  (OUT_LOSS + 2)

#define EPS_FLAG 6e-5f   // frozen (passed r3-r18, two-split screen)

typedef short bf16x8 __attribute__((ext_vector_type(8)));
typedef float f32x4  __attribute__((ext_vector_type(4)));
typedef const __attribute__((address_space(1))) void* gas_t;
typedef __attribute__((address_space(3))) void* las_t;

// ---- numpy fp32 semantics helpers (frozen from round 2 -- PASSED) ----------
__device__ __forceinline__ float sqb(float x) {
    float y = x * x;
    asm volatile("" : "+v"(y));
    return y;
}
#define NP_PAIRWISE_SQ64(GET, RES)                                     \
    do {                                                               \
        float r0 = sqb(GET(0)), r1 = sqb(GET(1)), r2 = sqb(GET(2)),    \
              r3 = sqb(GET(3)), r4 = sqb(GET(4)), r5 = sqb(GET(5)),    \
              r6 = sqb(GET(6)), r7 = sqb(GET(7));                      \
        _Pragma("unroll")                                              \
        for (int i = 8; i < 64; i += 8) {                              \
            r0 += sqb(GET(i + 0)); r1 += sqb(GET(i + 1));              \
            r2 += sqb(GET(i + 2)); r3 += sqb(GET(i + 3));              \
            r4 += sqb(GET(i + 4)); r5 += sqb(GET(i + 5));              \
            r6 += sqb(GET(i + 6)); r7 += sqb(GET(i + 7));              \
        }                                                              \
        RES = ((r0 + r1) + (r2 + r3)) + ((r4 + r5) + (r6 + r7));       \
    } while (0)

__device__ __forceinline__ unsigned short f2bf_rne(float x) {
    unsigned u = __float_as_uint(x);
    u += 0x7FFFu + ((u >> 16) & 1u);
    return (unsigned short)(u >> 16);
}
__device__ __forceinline__ float bf2f(unsigned short b) {
    return __uint_as_float(((unsigned)b) << 16);
}

// ws layout (bytes):
//   0:      sse double
//   64:     counts int[1024*16]  (64 KiB padded)
//   65600:  done int
//   65664:  h float[1024]
//   69760:  ch bf16[1024*64]   (128 KiB)
//   200832: cl bf16[1024*64]   (128 KiB)
//   331904: aux int[NTOK]      (512 KiB: i2 | deep<<31, flagged tokens only)

// Kernel 0: two-split prep (r18 verbatim); block 0 zeroes accums.
__global__ void vq_prep(const float* __restrict__ cb, float* __restrict__ h,
                        unsigned short* __restrict__ ch, unsigned short* __restrict__ cl,
                        double* __restrict__ sse, int* __restrict__ counts,
                        int* __restrict__ done) {
    if (blockIdx.x == 0) {
        if (threadIdx.x == 0) { *sse = 0.0; *done = 0; }
        for (int i = threadIdx.x; i < NEMB * 16; i += 256) counts[i] = 0;
    }
    int k = blockIdx.x * 256 + threadIdx.x;
    if (k >= NEMB) return;
    float c[64];
    const float4* p = (const float4*)(cb + k * DIM);
#pragma unroll
    for (int q = 0; q < 16; ++q) {
        float4 v = p[q];
        c[4 * q] = v.x; c[4 * q + 1] = v.y; c[4 * q + 2] = v.z; c[4 * q + 3] = v.w;
    }
    float hk;
#define GETC(d) (c[d])
    NP_PAIRWISE_SQ64(GETC, hk);
#undef GETC
    h[k] = hk;
#pragma unroll
    for (int b = 0; b < 8; ++b) {
        unsigned uhv[4], ulv[4];
#pragma unroll
        for (int e = 0; e < 4; ++e) {
            float x0 = -2.0f * c[b * 8 + e * 2 + 0];
            float x1 = -2.0f * c[b * 8 + e * 2 + 1];
            unsigned short h0 = f2bf_rne(x0), h1 = f2bf_rne(x1);
            unsigned short l0 = f2bf_rne(x0 - bf2f(h0)), l1 = f2bf_rne(x1 - bf2f(h1));
            uhv[e] = (unsigned)h0 | ((unsigned)h1 << 16);
            ulv[e] = (unsigned)l0 | ((unsigned)l1 << 16);
        }
        *(uint4*)(ch + k * 64 + b * 8) = make_uint4(uhv[0], uhv[1], uhv[2], uhv[3]);
        *(uint4*)(cl + k * 64 + b * 8) = make_uint4(ulv[0], ulv[1], ulv[2], ulv[3]);
    }
}

// Kernel 1: MFMA screen = r18 core (two-split, 3-buffer counted-vmcnt,
// pre-swizzled gload_lds) + TOP-3 tracking (m1,i1,m2,i2,m3). Flagged token:
// idx sign-encoded + aux[t] = i2 | deep<<31. Register-fed gather epilogue.
__global__ __launch_bounds__(512) void vq_screen(
    const float*          __restrict__ ze,
    const float*          __restrict__ cb,
    const unsigned short* __restrict__ ch_g,
    const unsigned short* __restrict__ cl_g,
    const float*          __restrict__ h_g,
    float*                __restrict__ out,
    int*                  __restrict__ aux,
    double*               __restrict__ sse_g,
    int*                  __restrict__ counts) {
    __shared__ __align__(16) char lds[53376];
    const int tid  = threadIdx.x;
    const int lane = tid & 63;
    const int wid  = tid >> 6;
    const int col  = lane & 15;
    const int grp  = lane >> 4;
    const int tbase = blockIdx.x * 256 + wid * 32;

    const int srow = tid >> 3, scol = tid & 7;
    const int srcoff = (srow * 8 + (scol ^ (srow & 7))) * 16;

    bf16x8 zh[2][2], zl[2][2];
#pragma unroll
    for (int tt = 0; tt < 2; ++tt)
#pragma unroll
        for (int s = 0; s < 2; ++s) {
            const float* zp = ze + (size_t)(tbase + tt * 16 + col) * 64 + s * 32 + grp * 8;
            float4 v0 = *(const float4*)(zp);
            float4 v1 = *(const float4*)(zp + 4);
            float zv[8] = {v0.x, v0.y, v0.z, v0.w, v1.x, v1.y, v1.z, v1.w};
            bf16x8 hfr, lfr;
#pragma unroll
            for (int j = 0; j < 8; ++j) {
                unsigned short hb = f2bf_rne(zv[j]);
                unsigned short lb = f2bf_rne(zv[j] - bf2f(hb));
                hfr[j] = (short)hb;
                lfr[j] = (short)lb;
            }
            zh[tt][s] = hfr;
            zl[tt][s] = lfr;
        }

    float m1[2] = {INFINITY, INFINITY}, m2[2] = {INFINITY, INFINITY};
    float m3[2] = {INFINITY, INFINITY};
    int   ki[2] = {0, 0}, i2[2] = {0, 0};

#define STAGE(cc, b)                                                           \
    do {                                                                       \
        __builtin_amdgcn_global_load_lds(                                      \
            (gas_t)((const char*)ch_g + (cc) * 8192 + srcoff),                 \
            (las_t)(lds + (b) * 16384 + wid * 1024), 16, 0, 0);                \
        __builtin_amdgcn_global_load_lds(                                      \
            (gas_t)((const char*)cl_g + (cc) * 8192 + srcoff),                 \
            (las_t)(lds + (b) * 16384 + 8192 + wid * 1024), 16, 0, 0);         \
    } while (0)

#define TOP3UPD(tt, s, kk)                                                     \
    do {                                                                       \
        bool lt1 = (s) < m1[tt], lt2 = (s) < m2[tt], lt3 = (s) < m3[tt];       \
        m3[tt] = lt2 ? m2[tt] : (lt3 ? (s) : m3[tt]);                          \
        i2[tt] = lt1 ? ki[tt] : (lt2 ? (kk) : i2[tt]);                         \
        m2[tt] = lt1 ? m1[tt] : (lt2 ? (s) : m2[tt]);                          \
        ki[tt] = lt1 ? (kk) : ki[tt];                                          \
        m1[tt] = lt1 ? (s) : m1[tt];                                           \
    } while (0)

#define COMPUTE(cc, b)                                                         \
    do {                                                                       \
        _Pragma("unroll")                                                      \
        for (int ct = 0; ct < 4; ++ct) {                                       \
            const int arow = (b) * 16384 + ct * 2048 + col * 128;              \
            bf16x8 ach0 = *(const bf16x8*)(lds + arow + ((((0 * 4) + grp) ^ (col & 7)) << 4)); \
            bf16x8 ach1 = *(const bf16x8*)(lds + arow + ((((1 * 4) + grp) ^ (col & 7)) << 4)); \
            bf16x8 acl0 = *(const bf16x8*)(lds + arow + 8192 + ((((0 * 4) + grp) ^ (col & 7)) << 4)); \
            bf16x8 acl1 = *(const bf16x8*)(lds + arow + 8192 + ((((1 * 4) + grp) ^ (col & 7)) << 4)); \
            f32x4 hv = *(const f32x4*)(lds + 49152 + (cc) * 256 + ct * 64 + grp * 16); \
            f32x4 acc0 = hv, acc1 = hv;                                        \
            acc0 = __builtin_amdgcn_mfma_f32_16x16x32_bf16(ach0, zh[0][0], acc0, 0, 0, 0); \
            acc1 = __builtin_amdgcn_mfma_f32_16x16x32_bf16(ach0, zh[1][0], acc1, 0, 0, 0); \
            acc0 = __builtin_amdgcn_mfma_f32_16x16x32_bf16(ach1, zh[0][1], acc0, 0, 0, 0); \
            acc1 = __builtin_amdgcn_mfma_f32_16x16x32_bf16(ach1, zh[1][1], acc1, 0, 0, 0); \
            acc0 = __builtin_amdgcn_mfma_f32_16x16x32_bf16(ach0, zl[0][0], acc0, 0, 0, 0); \
            acc1 = __builtin_amdgcn_mfma_f32_16x16x32_bf16(ach0, zl[1][0], acc1, 0, 0, 0); \
            acc0 = __builtin_amdgcn_mfma_f32_16x16x32_bf16(ach1, zl[0][1], acc0, 0, 0, 0); \
            acc1 = __builtin_amdgcn_mfma_f32_16x16x32_bf16(ach1, zl[1][1], acc1, 0, 0, 0); \
            acc0 = __builtin_amdgcn_mfma_f32_16x16x32_bf16(acl0, zh[0][0], acc0, 0, 0, 0); \
            acc1 = __builtin_amdgcn_mfma_f32_16x16x32_bf16(acl0, zh[1][0], acc1, 0, 0, 0); \
            acc0 = __builtin_amdgcn_mfma_f32_16x16x32_bf16(acl1, zh[0][1], acc0, 0, 0, 0); \
            acc1 = __builtin_amdgcn_mfma_f32_16x16x32_bf16(acl1, zh[1][1], acc1, 0, 0, 0); \
            const int kb = (cc) * 64 + ct * 16 + grp * 4;                      \
            _Pragma("unroll")                                                  \
            for (int j = 0; j < 4; ++j) {                                      \
                TOP3UPD(0, acc0[j], kb + j);                                   \
                TOP3UPD(1, acc1[j], kb + j);                                   \
            }                                                                  \
        }                                                                      \
    } while (0)

#define CHUNK(cc, W)                                                           \
    do {                                                                       \
        asm volatile("s_waitcnt vmcnt(" #W ")" ::: "memory");                  \
        __builtin_amdgcn_s_barrier();                                          \
        __builtin_amdgcn_sched_barrier(0);                                     \
        if ((cc) + 2 < 16) STAGE((cc) + 2, ((cc) + 2) % 3);                    \
        COMPUTE(cc, (cc) % 3);                                                 \
    } while (0)

    __builtin_amdgcn_global_load_lds((gas_t)(h_g + tid),
                                     (las_t)(lds + 49152 + wid * 256), 4, 0, 0);
    __builtin_amdgcn_global_load_lds((gas_t)(h_g + 512 + tid),
                                     (las_t)(lds + 49152 + 2048 + wid * 256), 4, 0, 0);
    STAGE(0, 0);
    STAGE(1, 1);

    CHUNK(0, 2);  CHUNK(1, 2);  CHUNK(2, 2);  CHUNK(3, 2);
    CHUNK(4, 2);  CHUNK(5, 2);  CHUNK(6, 2);  CHUNK(7, 2);
    CHUNK(8, 2);  CHUNK(9, 2);  CHUNK(10, 2); CHUNK(11, 2);
    CHUNK(12, 2); CHUNK(13, 2); CHUNK(14, 2); CHUNK(15, 0);

    // butterfly merge of (m1,i1,m2,i2,m3) across lane groups
#pragma unroll
    for (int d = 16; d <= 32; d <<= 1) {
#pragma unroll
        for (int tt = 0; tt < 2; ++tt) {
            float b1 = __shfl_xor(m1[tt], d, 64);
            float b2 = __shfl_xor(m2[tt], d, 64);
            float b3 = __shfl_xor(m3[tt], d, 64);
            int  jb1 = __shfl_xor(ki[tt], d, 64);
            int  jb2 = __shfl_xor(i2[tt], d, 64);
            bool sw  = b1 < m1[tt];
            float hi = sw ? m1[tt] : b1;
            int  jhi = sw ? ki[tt] : jb1;
            float c1 = sw ? b1 : m1[tt];
            int   j1 = sw ? jb1 : ki[tt];
            float mn2 = fminf(m2[tt], b2);
            int   jm2 = (m2[tt] <= b2) ? i2[tt] : jb2;
            float c2  = fminf(hi, mn2);
            int   j2  = (hi <= mn2) ? jhi : jm2;
            // median of {hi, m2[tt], b2}
            float mid = fmaxf(fminf(hi, m2[tt]),
                              fminf(fmaxf(hi, m2[tt]), b2));
            float c3  = fminf(mid, fminf(m3[tt], b3));
            m1[tt] = c1; ki[tt] = j1; m2[tt] = c2; i2[tt] = j2; m3[tt] = c3;
        }
    }
    unsigned flagpack = ((m2[0] - m1[0] < EPS_FLAG) ? 1u : 0u)
                      | ((m2[1] - m1[1] < EPS_FLAG) ? 2u : 0u);
    unsigned deeppack = ((m3[0] - m1[0] < EPS_FLAG) ? 1u : 0u)
                      | ((m3[1] - m1[1] < EPS_FLAG) ? 2u : 0u);
    if (lane < 16) {
#pragma unroll
        for (int tt = 0; tt < 2; ++tt) {
            int t = tbase + tt * 16 + lane;
            bool flag = (flagpack >> tt) & 1u;
            if (flag) {
                out[OUT_IDX + t] = -(float)(ki[tt] + 1);
                aux[t] = (int)((unsigned)i2[tt]
                               | (((deeppack >> tt) & 1u) << 31));
            } else {
                out[OUT_IDX + t] = (float)ki[tt];
            }
        }
    }

    // register-fed float4 gather/SSE/histogram for UNFLAGGED tokens (r16)
    double lsse = 0.0;
    const int d4 = lane & 15;
#pragma unroll
    for (int iter = 0; iter < 8; ++iter) {
        const int j   = iter * 4 + grp;
        const int tt  = iter >> 2;
        const int src = j & 15;
        int k = __shfl(ki[tt], src, 64);
        unsigned fp = __shfl(flagpack, src, 64);
        if (!((fp >> tt) & 1u)) {
            const int t = tbase + j;
            float4 q  = *(const float4*)(cb + k * DIM + d4 * 4);
            float4 zv = *(const float4*)(ze + (size_t)t * DIM + d4 * 4);
            *(float4*)(out + (size_t)t * DIM + d4 * 4) = q;
            double dx = (double)q.x - (double)zv.x;
            double dy = (double)q.y - (double)zv.y;
            double dz = (double)q.z - (double)zv.z;
            double dw = (double)q.w - (double)zv.w;
            lsse = fma(dx, dx, lsse); lsse = fma(dy, dy, lsse);
            lsse = fma(dz, dz, lsse); lsse = fma(dw, dw, lsse);
            if (d4 == 0) atomicAdd(&counts[k * 16], 1);
        }
    }
#pragma unroll
    for (int off = 32; off > 0; off >>= 1)
        lsse += __shfl_down(lsse, off, 64);
    double* red = (double*)(lds + 53312);
    if (lane == 0) red[wid] = lsse;
    __syncthreads();
    if (tid == 0) {
        double bs = ((red[0] + red[1]) + (red[2] + red[3]))
                  + ((red[4] + red[5]) + (red[6] + red[7]));
        atomicAdd(sse_g, bs);
    }
}

// Kernel 2: candidate rescue. Block owns 512 tokens; local worklist; each
// flagged non-deep token = ONE LANE computing exact np-formula d for {i1,i2}
// (no codebook scan!). Deep tokens (m3 tie, ~0.03%): wave-per-token full
// exact scan from GLOBAL cb (r8 math verbatim). Epilogue: wave row-copies,
// SSE, counts; done-counter last-block finalize.
__global__ __launch_bounds__(512) void vq_rescue(
    const float* __restrict__ ze, const float* __restrict__ cb,
    const float* __restrict__ h_g, const int* __restrict__ aux,
    float* __restrict__ out, double* __restrict__ sse_g,
    int* __restrict__ counts, int* __restrict__ done) {
    __shared__ int loc[512];
    __shared__ int kfin[512];
    __shared__ int dlist[512];
    __shared__ int nloc, ndeep;
    __shared__ float zst[8][64];
    __shared__ double red2[512];   // also used for block SSE reduce + finalize
    __shared__ int flagS;
    const int tid  = threadIdx.x;
    const int lane = tid & 63;
    const int wid  = tid >> 6;
    const int tbase = blockIdx.x * 512;

    if (tid == 0) { nloc = 0; ndeep = 0; }
    __syncthreads();
    {
        float fidx = out[OUT_IDX + tbase + tid];
        if (fidx < 0.0f) { int s = atomicAdd(&nloc, 1); loc[s] = tid; }
    }
    __syncthreads();
    const int nq = nloc;
    double lsse = 0.0;

    if (nq > 0) {
        // ---- phase A: one thread per entry (spread across waves) ----
        const int e = lane * 8 + wid;   // bijective 0..511
        if (e < nq) {
            const int t = tbase + loc[e];
            const int i1 = (int)(-out[OUT_IDX + t]) - 1;
            const unsigned a = (unsigned)aux[t];
            if (a >> 31) {
                int s = atomicAdd(&ndeep, 1);
                dlist[s] = e;
            } else {
                const int i2v = (int)(a & 1023u);
                const float4* zp  = (const float4*)(ze + (size_t)t * 64);
                const float4* c1p = (const float4*)(cb + i1 * 64);
                const float4* c2p = (const float4*)(cb + i2v * 64);
                float r0 = 0, r1 = 0, r2 = 0, r3 = 0, r4 = 0, r5 = 0, r6 = 0, r7 = 0;
                float A1 = 0.f, A2 = 0.f;
#pragma unroll
                for (int q = 0; q < 16; ++q) {
                    float4 zv = zp[q], cv1 = c1p[q], cv2 = c2p[q];
                    if (q & 1) {
                        r4 += sqb(zv.x); r5 += sqb(zv.y);
                        r6 += sqb(zv.z); r7 += sqb(zv.w);
                    } else {
                        r0 += sqb(zv.x); r1 += sqb(zv.y);
                        r2 += sqb(zv.z); r3 += sqb(zv.w);
                    }
                    A1 = fmaf(cv1.x, zv.x, A1); A1 = fmaf(cv1.y, zv.y, A1);
                    A1 = fmaf(cv1.z, zv.z, A1); A1 = fmaf(cv1.w, zv.w, A1);
                    A2 = fmaf(cv2.x, zv.x, A2); A2 = fmaf(cv2.y, zv.y, A2);
                    A2 = fmaf(cv2.z, zv.z, A2); A2 = fmaf(cv2.w, zv.w, A2);
                }
                float sz = ((r0 + r1) + (r2 + r3)) + ((r4 + r5) + (r6 + r7));
                float d1 = (sz + h_g[i1])  - 2.0f * A1;   // frozen np formula
                float d2 = (sz + h_g[i2v]) - 2.0f * A2;
                unsigned long long k1 =
                    ((unsigned long long)__float_as_uint(d1) << 32) | (unsigned)i1;
                unsigned long long k2 =
                    ((unsigned long long)__float_as_uint(d2) << 32) | (unsigned)i2v;
                kfin[e] = (int)(unsigned)((k1 < k2 ? k1 : k2) & 0xFFFFFFFFull);
            }
        }
        __syncthreads();

        // ---- phase B: deep tokens, wave per entry, full scan from global ----
        for (int i = wid; i < ndeep; i += 8) {
            const int e2 = dlist[i];
            const int t = tbase + loc[e2];
            zst[wid][lane] = ze[(size_t)t * 64 + lane];
            __builtin_amdgcn_wave_barrier();
            asm volatile("s_waitcnt lgkmcnt(0)" ::: "memory");
            __builtin_amdgcn_sched_barrier(0);
            float sz;
#define GZ(d) (zst[wid][d])
            NP_PAIRWISE_SQ64(GZ, sz);
#undef GZ
            const float4* cb4 = (const float4*)cb;
            const float4* zr4 = (const float4*)zst[wid];
            unsigned long long key = ~0ull;
            for (int cc = 0; cc < 16; ++cc) {
                const int code = lane + 64 * cc;
                float acc = 0.f;
#pragma unroll
                for (int d4i = 0; d4i < 16; ++d4i) {
                    float4 zq = zr4[d4i];
                    float4 cv = cb4[(size_t)code * 16 + d4i];
                    acc = fmaf(cv.x, zq.x, acc); acc = fmaf(cv.y, zq.y, acc);
                    acc = fmaf(cv.z, zq.z, acc); acc = fmaf(cv.w, zq.w, acc);
                }
                float dk = (sz + h_g[code]) - 2.0f * acc;
                unsigned long long c =
                    ((unsigned long long)__float_as_uint(dk) << 32) | (unsigned)code;
                key = c < key ? c : key;
            }
#pragma unroll
            for (int dd = 1; dd < 64; dd <<= 1) {
                unsigned long long o = __shfl_xor(key, dd, 64);
                key = o < key ? o : key;
            }
            if (lane == 0) kfin[e2] = (int)(unsigned)(key & 0xFFFFFFFFull);
        }
        __syncthreads();

        // ---- phase C: epilogue, wave per entry: row copy + SSE + counts ----
        for (int e3 = wid; e3 < nq; e3 += 8) {
            const int k = kfin[e3];
            const int t = tbase + loc[e3];
            float q  = cb[k * 64 + lane];
            float zv = ze[(size_t)t * 64 + lane];
            out[(size_t)t * 64 + lane] = q;
            double diff = (double)q - (double)zv;
            lsse = fma(diff, diff, lsse);
            if (lane == 0) {
                out[OUT_IDX + t] = (float)k;
                atomicAdd(&counts[k * 16], 1);
            }
        }
    }

#pragma unroll
    for (int off = 32; off > 0; off >>= 1)
        lsse += __shfl_down(lsse, off, 64);
    if (lane == 0) red2[wid] = lsse;
    __syncthreads();
    if (tid == 0) {
        double bs = ((red2[0] + red2[1]) + (red2[2] + red2[3]))
                  + ((red2[4] + red2[5]) + (red2[6] + red2[7]));
        if (bs != 0.0) atomicAdd(sse_g, bs);
        __threadfence();
        flagS = (atomicAdd(done, 1) == 255);
    }
    __syncthreads();

    if (flagS) {
        __threadfence();
        double local = 0.0;
        for (int k = tid; k < NEMB; k += 512) {
            int cv = __hip_atomic_load(&counts[k * 16], __ATOMIC_RELAXED, __HIP_MEMORY_SCOPE_AGENT);
            double p = (double)cv / (double)NTOK;
            local += p * log(p + 1e-10);
        }
        red2[tid] = local;
        __syncthreads();
        for (int s = 256; s > 0; s >>= 1) {
            if (tid < s) red2[tid] += red2[tid + s];
            __syncthreads();
        }
        if (tid == 0) {
            double sv = __hip_atomic_load(sse_g, __ATOMIC_RELAXED, __HIP_MEMORY_SCOPE_AGENT);
            double mse = sv / ((double)NTOK * (double)DIM);
            out[OUT_LOSS] = (float)(1.25 * mse);
            out[OUT_PERP] = (float)exp(-red2[0]);
        }
    }
}

extern "C" void kernel_launch(void* const* d_in, const int* in_sizes, int n_in,
                              void* d_out, int out_size, void* d_ws, size_t ws_size,
                              hipStream_t stream) {
    const float* ze = (const float*)d_in[0];
    const float* cb = (const float*)d_in[1];
    float* out = (float*)d_out;

    char* w = (char*)d_ws;
    double*         sse    = (double*)w;                     // @0
    int*            counts = (int*)(w + 64);                 // 64 KiB (padded)
    int*            done   = (int*)(w + 65600);
    float*          h      = (float*)(w + 65664);            // 4 KiB
    unsigned short* ch     = (unsigned short*)(w + 69760);   // 128 KiB
    unsigned short* cl     = (unsigned short*)(w + 200832);  // 128 KiB
    int*            aux    = (int*)(w + 331904);             // 512 KiB

    vq_prep<<<NEMB / 256, 256, 0, stream>>>(cb, h, ch, cl, sse, counts, done);
    vq_screen<<<NTOK / 256, 512, 0, stream>>>(ze, cb, ch, cl, h, out, aux, sse, counts);
    vq_rescue<<<NTOK / 512, 512, 0, stream>>>(ze, cb, h, aux, out, sse, counts, done);
}

// Round 22
// 116.527 us; speedup vs baseline: 1.3473x; 1.1470x over previous
//
#include <hip/hip_runtime.h>
#include <math.h>

// VectorQuantizer: N=131072 tokens, K=1024 codes, D=64, fp32.
// Out layout (flat): z_q_st[N*D] | loss | perplexity | indices[N] (as f32)
#define NTOK 131072
#define NEMB 1024
#define DIM  64
#define OUT_LOSS (NTOK * DIM)
#define OUT_PERP (OUT_LOSS + 1)
#define OUT_IDX  (OUT_LOSS + 2)

// r22: packed top-3 screen. Error budget: bf16 split ~5e-6 + formula ~4e-6 +
// bias accum ~4e-7 + 8-bit quantization 1.5e-5 => per-score |np - q| <= 2.4e-5;
// candidates need 2x = 4.8e-5 < EPS. Ties always flag -> rescue exact.
#define EPS_FLAG 8e-5f

typedef short bf16x8 __attribute__((ext_vector_type(8)));
typedef float f32x4  __attribute__((ext_vector_type(4)));
typedef const __attribute__((address_space(1))) void* gas_t;
typedef __attribute__((address_space(3))) void* las_t;

// ---- numpy fp32 semantics helpers (frozen from round 2 -- PASSED) ----------
__device__ __forceinline__ float sqb(float x) {
    float y = x * x;
    asm volatile("" : "+v"(y));
    return y;
}
#define NP_PAIRWISE_SQ64(GET, RES)                                     \
    do {                                                               \
        float r0 = sqb(GET(0)), r1 = sqb(GET(1)), r2 = sqb(GET(2)),    \
              r3 = sqb(GET(3)), r4 = sqb(GET(4)), r5 = sqb(GET(5)),    \
              r6 = sqb(GET(6)), r7 = sqb(GET(7));                      \
        _Pragma("unroll")                                              \
        for (int i = 8; i < 64; i += 8) {                              \
            r0 += sqb(GET(i + 0)); r1 += sqb(GET(i + 1));              \
            r2 += sqb(GET(i + 2)); r3 += sqb(GET(i + 3));              \
            r4 += sqb(GET(i + 4)); r5 += sqb(GET(i + 5));              \
            r6 += sqb(GET(i + 6)); r7 += sqb(GET(i + 7));              \
        }                                                              \
        RES = ((r0 + r1) + (r2 + r3)) + ((r4 + r5) + (r6 + r7));       \
    } while (0)

__device__ __forceinline__ unsigned short f2bf_rne(float x) {
    unsigned u = __float_as_uint(x);
    u += 0x7FFFu + ((u >> 16) & 1u);
    return (unsigned short)(u >> 16);
}
__device__ __forceinline__ float bf2f(unsigned short b) {
    return __uint_as_float(((unsigned)b) << 16);
}
__device__ __forceinline__ float med3f(float a, float b, float c) {
    float r;
    asm("v_med3_f32 %0, %1, %2, %3" : "=v"(r) : "v"(a), "v"(b), "v"(c));
    return r;
}

// ws layout (bytes):
//   0:      sse double
//   64:     counts int[1024*16] (64 KiB padded)
//   65600:  done int
//   65664:  h float[1024]       (original, rescue np formula)
//   69760:  hb float[1024]      (h + 0.5, screen bias)
//   73856:  ch bf16[1024*64]    (128 KiB)
//   204928: cl bf16[1024*64]    (128 KiB)
//   336000: aux int[NTOK]       (512 KiB: i2 | deep<<31)

// Kernel 0: two-split prep + hb = h + 0.5f; block 0 zeroes accums.
__global__ void vq_prep(const float* __restrict__ cb, float* __restrict__ h,
                        float* __restrict__ hb,
                        unsigned short* __restrict__ ch, unsigned short* __restrict__ cl,
                        double* __restrict__ sse, int* __restrict__ counts,
                        int* __restrict__ done) {
    if (blockIdx.x == 0) {
        if (threadIdx.x == 0) { *sse = 0.0; *done = 0; }
        for (int i = threadIdx.x; i < NEMB * 16; i += 256) counts[i] = 0;
    }
    int k = blockIdx.x * 256 + threadIdx.x;
    if (k >= NEMB) return;
    float c[64];
    const float4* p = (const float4*)(cb + k * DIM);
#pragma unroll
    for (int q = 0; q < 16; ++q) {
        float4 v = p[q];
        c[4 * q] = v.x; c[4 * q + 1] = v.y; c[4 * q + 2] = v.z; c[4 * q + 3] = v.w;
    }
    float hk;
#define GETC(d) (c[d])
    NP_PAIRWISE_SQ64(GETC, hk);
#undef GETC
    h[k] = hk;
    hb[k] = hk + 0.5f;
#pragma unroll
    for (int b = 0; b < 8; ++b) {
        unsigned uhv[4], ulv[4];
#pragma unroll
        for (int e = 0; e < 4; ++e) {
            float x0 = -2.0f * c[b * 8 + e * 2 + 0];
            float x1 = -2.0f * c[b * 8 + e * 2 + 1];
            unsigned short h0 = f2bf_rne(x0), h1 = f2bf_rne(x1);
            unsigned short l0 = f2bf_rne(x0 - bf2f(h0)), l1 = f2bf_rne(x1 - bf2f(h1));
            uhv[e] = (unsigned)h0 | ((unsigned)h1 << 16);
            ulv[e] = (unsigned)l0 | ((unsigned)l1 << 16);
        }
        *(uint4*)(ch + k * 64 + b * 8) = make_uint4(uhv[0], uhv[1], uhv[2], uhv[3]);
        *(uint4*)(cl + k * 64 + b * 8) = make_uint4(ulv[0], ulv[1], ulv[2], ulv[3]);
    }
}

// Kernel 1: MFMA screen, r18 core + PACKED top-3: acc preloaded with h+0.5
// (scores in [0.3,0.7], monotone bits); low 8 mantissa bits replaced by the
// lane-local (cc,ct,j) index; track sorted (m1,m2,m3) via min + 2x v_med3 =
// 5 VALU ops/score (r18 parity) with indices embedded. Unpack before the
// r21-verified butterfly merge. Flag/deep/aux + register-fed gather (r16).
__global__ __launch_bounds__(512) void vq_screen(
    const float*          __restrict__ ze,
    const float*          __restrict__ cb,
    const unsigned short* __restrict__ ch_g,
    const unsigned short* __restrict__ cl_g,
    const float*          __restrict__ hb_g,
    float*                __restrict__ out,
    int*                  __restrict__ aux,
    double*               __restrict__ sse_g,
    int*                  __restrict__ counts) {
    __shared__ __align__(16) char lds[53376];
    const int tid  = threadIdx.x;
    const int lane = tid & 63;
    const int wid  = tid >> 6;
    const int col  = lane & 15;
    const int grp  = lane >> 4;
    const int tbase = blockIdx.x * 256 + wid * 32;

    const int srow = tid >> 3, scol = tid & 7;
    const int srcoff = (srow * 8 + (scol ^ (srow & 7))) * 16;

    bf16x8 zh[2][2], zl[2][2];
#pragma unroll
    for (int tt = 0; tt < 2; ++tt)
#pragma unroll
        for (int s = 0; s < 2; ++s) {
            const float* zp = ze + (size_t)(tbase + tt * 16 + col) * 64 + s * 32 + grp * 8;
            float4 v0 = *(const float4*)(zp);
            float4 v1 = *(const float4*)(zp + 4);
            float zv[8] = {v0.x, v0.y, v0.z, v0.w, v1.x, v1.y, v1.z, v1.w};
            bf16x8 hfr, lfr;
#pragma unroll
            for (int j = 0; j < 8; ++j) {
                unsigned short hbv = f2bf_rne(zv[j]);
                unsigned short lbv = f2bf_rne(zv[j] - bf2f(hbv));
                hfr[j] = (short)hbv;
                lfr[j] = (short)lbv;
            }
            zh[tt][s] = hfr;
            zl[tt][s] = lfr;
        }

    float m1[2] = {INFINITY, INFINITY}, m2[2] = {INFINITY, INFINITY};
    float m3[2] = {INFINITY, INFINITY};

#define STAGE(cc, b)                                                           \
    do {                                                                       \
        __builtin_amdgcn_global_load_lds(                                      \
            (gas_t)((const char*)ch_g + (cc) * 8192 + srcoff),                 \
            (las_t)(lds + (b) * 16384 + wid * 1024), 16, 0, 0);                \
        __builtin_amdgcn_global_load_lds(                                      \
            (gas_t)((const char*)cl_g + (cc) * 8192 + srcoff),                 \
            (las_t)(lds + (b) * 16384 + 8192 + wid * 1024), 16, 0, 0);         \
    } while (0)

    // packed sorted-insert: 5 VALU ops, index embedded in low 8 bits
#define TOP3P(tt, sval, kidx)                                                  \
    do {                                                                       \
        unsigned _ub = (__float_as_uint(sval) & 0xFFFFFF00u) | (unsigned)(kidx); \
        float _u = __uint_as_float(_ub);                                       \
        float _t2 = med3f(m1[tt], m2[tt], _u);                                 \
        float _t3 = med3f(m2[tt], m3[tt], _u);                                 \
        m1[tt] = fminf(m1[tt], _u);                                            \
        m2[tt] = _t2; m3[tt] = _t3;                                            \
    } while (0)

#define COMPUTE(cc, b)                                                         \
    do {                                                                       \
        _Pragma("unroll")                                                      \
        for (int ct = 0; ct < 4; ++ct) {                                       \
            const int arow = (b) * 16384 + ct * 2048 + col * 128;              \
            bf16x8 ach0 = *(const bf16x8*)(lds + arow + ((((0 * 4) + grp) ^ (col & 7)) << 4)); \
            bf16x8 ach1 = *(const bf16x8*)(lds + arow + ((((1 * 4) + grp) ^ (col & 7)) << 4)); \
            bf16x8 acl0 = *(const bf16x8*)(lds + arow + 8192 + ((((0 * 4) + grp) ^ (col & 7)) << 4)); \
            bf16x8 acl1 = *(const bf16x8*)(lds + arow + 8192 + ((((1 * 4) + grp) ^ (col & 7)) << 4)); \
            f32x4 hv = *(const f32x4*)(lds + 49152 + (cc) * 256 + ct * 64 + grp * 16); \
            f32x4 acc0 = hv, acc1 = hv;                                        \
            acc0 = __builtin_amdgcn_mfma_f32_16x16x32_bf16(ach0, zh[0][0], acc0, 0, 0, 0); \
            acc1 = __builtin_amdgcn_mfma_f32_16x16x32_bf16(ach0, zh[1][0], acc1, 0, 0, 0); \
            acc0 = __builtin_amdgcn_mfma_f32_16x16x32_bf16(ach1, zh[0][1], acc0, 0, 0, 0); \
            acc1 = __builtin_amdgcn_mfma_f32_16x16x32_bf16(ach1, zh[1][1], acc1, 0, 0, 0); \
            acc0 = __builtin_amdgcn_mfma_f32_16x16x32_bf16(ach0, zl[0][0], acc0, 0, 0, 0); \
            acc1 = __builtin_amdgcn_mfma_f32_16x16x32_bf16(ach0, zl[1][0], acc1, 0, 0, 0); \
            acc0 = __builtin_amdgcn_mfma_f32_16x16x32_bf16(ach1, zl[0][1], acc0, 0, 0, 0); \
            acc1 = __builtin_amdgcn_mfma_f32_16x16x32_bf16(ach1, zl[1][1], acc1, 0, 0, 0); \
            acc0 = __builtin_amdgcn_mfma_f32_16x16x32_bf16(acl0, zh[0][0], acc0, 0, 0, 0); \
            acc1 = __builtin_amdgcn_mfma_f32_16x16x32_bf16(acl0, zh[1][0], acc1, 0, 0, 0); \
            acc0 = __builtin_amdgcn_mfma_f32_16x16x32_bf16(acl1, zh[0][1], acc0, 0, 0, 0); \
            acc1 = __builtin_amdgcn_mfma_f32_16x16x32_bf16(acl1, zh[1][1], acc1, 0, 0, 0); \
            _Pragma("unroll")                                                  \
            for (int j = 0; j < 4; ++j) {                                      \
                const int kidx = ((cc) << 4) | (ct << 2) | j;                  \
                TOP3P(0, acc0[j], kidx);                                       \
                TOP3P(1, acc1[j], kidx);                                       \
            }                                                                  \
        }                                                                      \
    } while (0)

#define CHUNK(cc, W)                                                           \
    do {                                                                       \
        asm volatile("s_waitcnt vmcnt(" #W ")" ::: "memory");                  \
        __builtin_amdgcn_s_barrier();                                          \
        __builtin_amdgcn_sched_barrier(0);                                     \
        if ((cc) + 2 < 16) STAGE((cc) + 2, ((cc) + 2) % 3);                    \
        COMPUTE(cc, (cc) % 3);                                                 \
    } while (0)

    __builtin_amdgcn_global_load_lds((gas_t)(hb_g + tid),
                                     (las_t)(lds + 49152 + wid * 256), 4, 0, 0);
    __builtin_amdgcn_global_load_lds((gas_t)(hb_g + 512 + tid),
                                     (las_t)(lds + 49152 + 2048 + wid * 256), 4, 0, 0);
    STAGE(0, 0);
    STAGE(1, 1);

    CHUNK(0, 2);  CHUNK(1, 2);  CHUNK(2, 2);  CHUNK(3, 2);
    CHUNK(4, 2);  CHUNK(5, 2);  CHUNK(6, 2);  CHUNK(7, 2);
    CHUNK(8, 2);  CHUNK(9, 2);  CHUNK(10, 2); CHUNK(11, 2);
    CHUNK(12, 2); CHUNK(13, 2); CHUNK(14, 2); CHUNK(15, 0);

    // unpack lane-local packed values -> (quantized score, global k)
    float q1[2], q2[2], q3[2];
    int   ki[2], i2[2];
#pragma unroll
    for (int tt = 0; tt < 2; ++tt) {
        unsigned b1 = __float_as_uint(m1[tt]);
        unsigned b2 = __float_as_uint(m2[tt]);
        unsigned b3 = __float_as_uint(m3[tt]);
        q1[tt] = __uint_as_float(b1 & 0xFFFFFF00u);
        q2[tt] = __uint_as_float(b2 & 0xFFFFFF00u);
        q3[tt] = __uint_as_float(b3 & 0xFFFFFF00u);
        unsigned e1 = b1 & 255u, e2 = b2 & 255u;
        ki[tt] = (int)((e1 >> 4) * 64 + ((e1 >> 2) & 3u) * 16 + grp * 4 + (e1 & 3u));
        i2[tt] = (int)((e2 >> 4) * 64 + ((e2 >> 2) & 3u) * 16 + grp * 4 + (e2 & 3u));
    }

    // butterfly merge of (q1,ki,q2,i2,q3) across lane groups (r21, PASSED)
#pragma unroll
    for (int d = 16; d <= 32; d <<= 1) {
#pragma unroll
        for (int tt = 0; tt < 2; ++tt) {
            float b1 = __shfl_xor(q1[tt], d, 64);
            float b2 = __shfl_xor(q2[tt], d, 64);
            float b3 = __shfl_xor(q3[tt], d, 64);
            int  jb1 = __shfl_xor(ki[tt], d, 64);
            int  jb2 = __shfl_xor(i2[tt], d, 64);
            bool sw  = b1 < q1[tt];
            float hi = sw ? q1[tt] : b1;
            int  jhi = sw ? ki[tt] : jb1;
            float c1 = sw ? b1 : q1[tt];
            int   j1 = sw ? jb1 : ki[tt];
            float mn2 = fminf(q2[tt], b2);
            int   jm2 = (q2[tt] <= b2) ? i2[tt] : jb2;
            float c2  = fminf(hi, mn2);
            int   j2  = (hi <= mn2) ? jhi : jm2;
            float mid = fmaxf(fminf(hi, q2[tt]),
                              fminf(fmaxf(hi, q2[tt]), b2));
            float c3  = fminf(mid, fminf(q3[tt], b3));
            q1[tt] = c1; ki[tt] = j1; q2[tt] = c2; i2[tt] = j2; q3[tt] = c3;
        }
    }
    unsigned flagpack = ((q2[0] - q1[0] < EPS_FLAG) ? 1u : 0u)
                      | ((q2[1] - q1[1] < EPS_FLAG) ? 2u : 0u);
    unsigned deeppack = ((q3[0] - q1[0] < EPS_FLAG) ? 1u : 0u)
                      | ((q3[1] - q1[1] < EPS_FLAG) ? 2u : 0u);
    if (lane < 16) {
#pragma unroll
        for (int tt = 0; tt < 2; ++tt) {
            int t = tbase + tt * 16 + lane;
            bool flag = (flagpack >> tt) & 1u;
            if (flag) {
                out[OUT_IDX + t] = -(float)(ki[tt] + 1);
                aux[t] = (int)((unsigned)i2[tt]
                               | (((deeppack >> tt) & 1u) << 31));
            } else {
                out[OUT_IDX + t] = (float)ki[tt];
            }
        }
    }

    // register-fed float4 gather/SSE/histogram for UNFLAGGED tokens (r16)
    double lsse = 0.0;
    const int d4 = lane & 15;
#pragma unroll
    for (int iter = 0; iter < 8; ++iter) {
        const int j   = iter * 4 + grp;
        const int tt  = iter >> 2;
        const int src = j & 15;
        int k = __shfl(ki[tt], src, 64);
        unsigned fp = __shfl(flagpack, src, 64);
        if (!((fp >> tt) & 1u)) {
            const int t = tbase + j;
            float4 q  = *(const float4*)(cb + k * DIM + d4 * 4);
            float4 zv = *(const float4*)(ze + (size_t)t * DIM + d4 * 4);
            *(float4*)(out + (size_t)t * DIM + d4 * 4) = q;
            double dx = (double)q.x - (double)zv.x;
            double dy = (double)q.y - (double)zv.y;
            double dz = (double)q.z - (double)zv.z;
            double dw = (double)q.w - (double)zv.w;
            lsse = fma(dx, dx, lsse); lsse = fma(dy, dy, lsse);
            lsse = fma(dz, dz, lsse); lsse = fma(dw, dw, lsse);
            if (d4 == 0) atomicAdd(&counts[k * 16], 1);
        }
    }
#pragma unroll
    for (int off = 32; off > 0; off >>= 1)
        lsse += __shfl_down(lsse, off, 64);
    double* red = (double*)(lds + 53312);
    if (lane == 0) red[wid] = lsse;
    __syncthreads();
    if (tid == 0) {
        double bs = ((red[0] + red[1]) + (red[2] + red[3]))
                  + ((red[4] + red[5]) + (red[6] + red[7]));
        atomicAdd(sse_g, bs);
    }
}

// Kernel 2: candidate rescue (r21 VERBATIM -- PASSED). Flagged non-deep:
// one lane, exact np-formula on {i1,i2}. Deep: wave full scan from global.
// Epilogue row copies + SSE + counts; done-counter last-block finalize.
__global__ __launch_bounds__(512) void vq_rescue(
    const float* __restrict__ ze, const float* __restrict__ cb,
    const float* __restrict__ h_g, const int* __restrict__ aux,
    float* __restrict__ out, double* __restrict__ sse_g,
    int* __restrict__ counts, int* __restrict__ done) {
    __shared__ int loc[512];
    __shared__ int kfin[512];
    __shared__ int dlist[512];
    __shared__ int nloc, ndeep;
    __shared__ float zst[8][64];
    __shared__ double red2[512];
    __shared__ int flagS;
    const int tid  = threadIdx.x;
    const int lane = tid & 63;
    const int wid  = tid >> 6;
    const int tbase = blockIdx.x * 512;

    if (tid == 0) { nloc = 0; ndeep = 0; }
    __syncthreads();
    {
        float fidx = out[OUT_IDX + tbase + tid];
        if (fidx < 0.0f) { int s = atomicAdd(&nloc, 1); loc[s] = tid; }
    }
    __syncthreads();
    const int nq = nloc;
    double lsse = 0.0;

    if (nq > 0) {
        const int e = lane * 8 + wid;
        if (e < nq) {
            const int t = tbase + loc[e];
            const int i1 = (int)(-out[OUT_IDX + t]) - 1;
            const unsigned a = (unsigned)aux[t];
            if (a >> 31) {
                int s = atomicAdd(&ndeep, 1);
                dlist[s] = e;
            } else {
                const int i2v = (int)(a & 1023u);
                const float4* zp  = (const float4*)(ze + (size_t)t * 64);
                const float4* c1p = (const float4*)(cb + i1 * 64);
                const float4* c2p = (const float4*)(cb + i2v * 64);
                float r0 = 0, r1 = 0, r2 = 0, r3 = 0, r4 = 0, r5 = 0, r6 = 0, r7 = 0;
                float A1 = 0.f, A2 = 0.f;
#pragma unroll
                for (int q = 0; q < 16; ++q) {
                    float4 zv = zp[q], cv1 = c1p[q], cv2 = c2p[q];
                    if (q & 1) {
                        r4 += sqb(zv.x); r5 += sqb(zv.y);
                        r6 += sqb(zv.z); r7 += sqb(zv.w);
                    } else {
                        r0 += sqb(zv.x); r1 += sqb(zv.y);
                        r2 += sqb(zv.z); r3 += sqb(zv.w);
                    }
                    A1 = fmaf(cv1.x, zv.x, A1); A1 = fmaf(cv1.y, zv.y, A1);
                    A1 = fmaf(cv1.z, zv.z, A1); A1 = fmaf(cv1.w, zv.w, A1);
                    A2 = fmaf(cv2.x, zv.x, A2); A2 = fmaf(cv2.y, zv.y, A2);
                    A2 = fmaf(cv2.z, zv.z, A2); A2 = fmaf(cv2.w, zv.w, A2);
                }
                float sz = ((r0 + r1) + (r2 + r3)) + ((r4 + r5) + (r6 + r7));
                float d1 = (sz + h_g[i1])  - 2.0f * A1;
                float d2 = (sz + h_g[i2v]) - 2.0f * A2;
                unsigned long long k1 =
                    ((unsigned long long)__float_as_uint(d1) << 32) | (unsigned)i1;
                unsigned long long k2 =
                    ((unsigned long long)__float_as_uint(d2) << 32) | (unsigned)i2v;
                kfin[e] = (int)(unsigned)((k1 < k2 ? k1 : k2) & 0xFFFFFFFFull);
            }
        }
        __syncthreads();

        for (int i = wid; i < ndeep; i += 8) {
            const int e2 = dlist[i];
            const int t = tbase + loc[e2];
            zst[wid][lane] = ze[(size_t)t * 64 + lane];
            __builtin_amdgcn_wave_barrier();
            asm volatile("s_waitcnt lgkmcnt(0)" ::: "memory");
            __builtin_amdgcn_sched_barrier(0);
            float sz;
#define GZ(d) (zst[wid][d])
            NP_PAIRWISE_SQ64(GZ, sz);
#undef GZ
            const float4* cb4 = (const float4*)cb;
            const float4* zr4 = (const float4*)zst[wid];
            unsigned long long key = ~0ull;
            for (int cc = 0; cc < 16; ++cc) {
                const int code = lane + 64 * cc;
                float acc = 0.f;
#pragma unroll
                for (int d4i = 0; d4i < 16; ++d4i) {
                    float4 zq = zr4[d4i];
                    float4 cv = cb4[(size_t)code * 16 + d4i];
                    acc = fmaf(cv.x, zq.x, acc); acc = fmaf(cv.y, zq.y, acc);
                    acc = fmaf(cv.z, zq.z, acc); acc = fmaf(cv.w, zq.w, acc);
                }
                float dk = (sz + h_g[code]) - 2.0f * acc;
                unsigned long long c =
                    ((unsigned long long)__float_as_uint(dk) << 32) | (unsigned)code;
                key = c < key ? c : key;
            }
#pragma unroll
            for (int dd = 1; dd < 64; dd <<= 1) {
                unsigned long long o = __shfl_xor(key, dd, 64);
                key = o < key ? o : key;
            }
            if (lane == 0) kfin[e2] = (int)(unsigned)(key & 0xFFFFFFFFull);
        }
        __syncthreads();

        for (int e3 = wid; e3 < nq; e3 += 8) {
            const int k = kfin[e3];
            const int t = tbase + loc[e3];
            float q  = cb[k * 64 + lane];
            float zv = ze[(size_t)t * 64 + lane];
            out[(size_t)t * 64 + lane] = q;
            double diff = (double)q - (double)zv;
            lsse = fma(diff, diff, lsse);
            if (lane == 0) {
                out[OUT_IDX + t] = (float)k;
                atomicAdd(&counts[k * 16], 1);
            }
        }
    }

#pragma unroll
    for (int off = 32; off > 0; off >>= 1)
        lsse += __shfl_down(lsse, off, 64);
    if (lane == 0) red2[wid] = lsse;
    __syncthreads();
    if (tid == 0) {
        double bs = ((red2[0] + red2[1]) + (red2[2] + red2[3]))
                  + ((red2[4] + red2[5]) + (red2[6] + red2[7]));
        if (bs != 0.0) atomicAdd(sse_g, bs);
        __threadfence();
        flagS = (atomicAdd(done, 1) == 255);
    }
    __syncthreads();

    if (flagS) {
        __threadfence();
        double local = 0.0;
        for (int k = tid; k < NEMB; k += 512) {
            int cv = __hip_atomic_load(&counts[k * 16], __ATOMIC_RELAXED, __HIP_MEMORY_SCOPE_AGENT);
            double p = (double)cv / (double)NTOK;
            local += p * log(p + 1e-10);
        }
        red2[tid] = local;
        __syncthreads();
        for (int s = 256; s > 0; s >>= 1) {
            if (tid < s) red2[tid] += red2[tid + s];
            __syncthreads();
        }
        if (tid == 0) {
            double sv = __hip_atomic_load(sse_g, __ATOMIC_RELAXED, __HIP_MEMORY_SCOPE_AGENT);
            double mse = sv / ((double)NTOK * (double)DIM);
            out[OUT_LOSS] = (float)(1.25 * mse);
            out[OUT_PERP] = (float)exp(-red2[0]);
        }
    }
}

extern "C" void kernel_launch(void* const* d_in, const int* in_sizes, int n_in,
                              void* d_out, int out_size, void* d_ws, size_t ws_size,
                              hipStream_t stream) {
    const float* ze = (const float*)d_in[0];
    const float* cb = (const float*)d_in[1];
    float* out = (float*)d_out;

    char* w = (char*)d_ws;
    double*         sse    = (double*)w;                     // @0
    int*            counts = (int*)(w + 64);                 // 64 KiB (padded)
    int*            done   = (int*)(w + 65600);
    float*          h      = (float*)(w + 65664);            // 4 KiB
    float*          hb     = (float*)(w + 69760);            // 4 KiB
    unsigned short* ch     = (unsigned short*)(w + 73856);   // 128 KiB
    unsigned short* cl     = (unsigned short*)(w + 204928);  // 128 KiB
    int*            aux    = (int*)(w + 336000);             // 512 KiB

    vq_prep<<<NEMB / 256, 256, 0, stream>>>(cb, h, hb, ch, cl, sse, counts, done);
    vq_screen<<<NTOK / 256, 512, 0, stream>>>(ze, cb, ch, cl, hb, out, aux, sse, counts);
    vq_rescue<<<NTOK / 512, 512, 0, stream>>>(ze, cb, h, aux, out, sse, counts, done);
}